// Round 6
// baseline (79.832 us; speedup 1.0000x reference)
//
#include <hip/hip_runtime.h>
#include <cstddef>

#define BB 4
#define NN 256
#define HH 256
#define BN_EPS 1e-5f
#define ETA_EPS 1e-20f

typedef float f4 __attribute__((ext_vector_type(4)));

__device__ __forceinline__ float fast_sigmoid(float x) {
    float ex = __expf(-x);
    return __builtin_amdgcn_rcpf(1.f + ex);
}

// ---------------------------------------------------------------------------
// Kernel 0: transpose W1,W2 -> WT1,WT2 (WT[h][o] = W[o][h]). 32 blocks.
// ---------------------------------------------------------------------------
__global__ __launch_bounds__(256) void transpose_kernel(
    const float* __restrict__ W1, const float* __restrict__ W2,
    float* __restrict__ WT1, float* __restrict__ WT2)
{
    const int which = blockIdx.x >> 4;
    const int tile  = blockIdx.x & 15;
    const int tr = (tile >> 2) << 6, tc = (tile & 3) << 6;
    const float* __restrict__ W  = which ? W2 : W1;
    float* __restrict__ WT       = which ? WT2 : WT1;

    __shared__ float tl[64][65];
    const int c = threadIdx.x & 63, p0 = threadIdx.x >> 6;
#pragma unroll
    for (int p = 0; p < 16; ++p) {
        int r = p * 4 + p0;
        tl[c][r] = W[(tr + r) * HH + tc + c];
    }
    __syncthreads();
#pragma unroll
    for (int p = 0; p < 16; ++p) {
        int cc = p * 4 + p0;
        WT[(tc + cc) * HH + tr + c] = tl[cc][c];
    }
}

// ---------------------------------------------------------------------------
// Kernel 1: projections via WT.  out[r][o] = sum_h x[r][h] * WT[h][o].
// grid = 256 blocks: [0,128) -> WT1/xleft, [128,256) -> WT2/xw2. (R5 version)
// ---------------------------------------------------------------------------
__global__ __launch_bounds__(256) void proj_kernel(
    const float* __restrict__ nodes, const float* __restrict__ WT1,
    const float* __restrict__ WT2, float* __restrict__ xleft,
    float* __restrict__ xw2)
{
    const int which = blockIdx.x >> 7;
    const int rb    = blockIdx.x & 127;   // 8-row group
    const float* __restrict__ WT = which ? WT2 : WT1;
    float* __restrict__ out      = which ? xw2 : xleft;
    const int t = threadIdx.x;

    __shared__ float xs[8][HH];           // 8 KB
    {
        f4* xs4 = reinterpret_cast<f4*>(xs);
        const f4* nodes4 = reinterpret_cast<const f4*>(nodes) + rb * 512;
#pragma unroll
        for (int m = 0; m < 2; ++m) xs4[m * 256 + t] = nodes4[m * 256 + t];
    }
    __syncthreads();

    const int oq = t & 63;
    const int hg = t >> 6;
    const f4* __restrict__ WT4 = reinterpret_cast<const f4*>(WT);

    f4 acc[8];
#pragma unroll
    for (int r = 0; r < 8; ++r) acc[r] = (f4){0.f, 0.f, 0.f, 0.f};

    for (int hh = 0; hh < 64; ++hh) {
        const int h = hg * 64 + hh;
        f4 wv = WT4[h * 64 + oq];
#pragma unroll
        for (int r = 0; r < 8; ++r)
            acc[r] += xs[r][h] * wv;
    }

    __shared__ f4 ps[4][8][64];           // 32 KB
#pragma unroll
    for (int r = 0; r < 8; ++r) ps[hg][r][oq] = acc[r];
    __syncthreads();

#pragma unroll
    for (int m = 0; m < 2; ++m) {
        int idx = m * 256 + t;
        int r = idx >> 6, o = idx & 63;
        f4 v = ps[0][r][o] + ps[1][r][o] + ps[2][r][o] + ps[3][r][o];
        reinterpret_cast<f4*>(out)[(rb * 8 + r) * 64 + o] = v;
    }
}

// ---------------------------------------------------------------------------
// Kernel 2: edge aggregation, fully-contiguous streaming.
// grid = 1024 blocks x 512 thr. Block = one i-row; wave w = j-group of 32.
// Each wave-load reads ONE FULL 1 KB row edges[b,i,j,:] (64 lanes x 16 B
// contiguous), j sequential -> 32 KB contiguous stream per wave. No channel
// slicing (R5 split rows into 256 B chunks across 4 blocks -> DRAM-page
// inefficiency). xw read straight from L2 (256 KB/b, resident; R4 proved
// LDS staging buys nothing); edges nontemporal so the stream doesn't evict.
// Reduction: 16 KB LDS, 2-way-conflict layout, no shuffles.
// ---------------------------------------------------------------------------
__global__ __launch_bounds__(512, 6) void edge_kernel(
    const float* __restrict__ edges, const float* __restrict__ xw2,
    const float* __restrict__ xleft, float* __restrict__ equ)
{
    const int bi = blockIdx.x;         // b*N + i, 0..1023
    const int b  = bi >> 8;
    const int t  = threadIdx.x;
    const int q  = t & 63;             // f4 quad over ALL 256 channels
    const int jg = t >> 6;             // 0..7, j-group of 32

    const f4* __restrict__ e4 =
        reinterpret_cast<const f4*>(edges) + ((size_t)bi * NN + jg * 32) * 64 + q;
    const f4* __restrict__ xw4 =
        reinterpret_cast<const f4*>(xw2) + ((size_t)b * NN + jg * 32) * 64 + q;

    f4 s0 = (f4){0.f, 0.f, 0.f, 0.f};
    f4 s1 = (f4){0.f, 0.f, 0.f, 0.f};

#pragma unroll 2
    for (int jj = 0; jj < 32; ++jj) {
        f4 e  = __builtin_nontemporal_load(e4 + (size_t)jj * 64);
        f4 xw = xw4[(size_t)jj * 64];
#pragma unroll
        for (int k = 0; k < 4; ++k) {
            float sg = fast_sigmoid(e[k]);
            s0[k] += sg;
            s1[k] += sg * xw[k];
        }
    }

    __shared__ f4 red0[8][64];         // 8 KB, [jg][q]: lanes consecutive -> 2-way
    __shared__ f4 red1[8][64];         // 8 KB
    red0[jg][q] = s0;
    red1[jg][q] = s1;
    __syncthreads();

    if (t < 64) {
        f4 S0 = (f4){0.f, 0.f, 0.f, 0.f};
        f4 S1 = (f4){0.f, 0.f, 0.f, 0.f};
#pragma unroll
        for (int g = 0; g < 8; ++g) { S0 += red0[g][t]; S1 += red1[g][t]; }
        f4 xl = reinterpret_cast<const f4*>(xleft)[bi * 64 + t];
        f4 o;
#pragma unroll
        for (int k = 0; k < 4; ++k) o[k] = xl[k] + S1[k] / (S0[k] + ETA_EPS);
        reinterpret_cast<f4*>(equ)[bi * 64 + t] = o;
    }
}

// ---------------------------------------------------------------------------
// Kernel 3: fused BN stats + normalize. 64 blocks x 1024 thr; block owns one
// f4 channel quad (4 channels). Thread t holds equ row t's quad in a register
// across both phases (no re-read). Wave shuffle-reduce (deterministic), wave
// leaders -> LDS, thread 0 finalizes, broadcast scale/shift via LDS, apply.
// equ column reads are 16B-strided (only 1 MB total -> ~8 MB line traffic).
// ---------------------------------------------------------------------------
__global__ __launch_bounds__(1024) void statsnorm_kernel(
    const float* __restrict__ equ, const float* __restrict__ gamma,
    const float* __restrict__ beta, float* __restrict__ out)
{
    const int cq = blockIdx.x;          // channel quad 0..63
    const int t  = threadIdx.x;         // row 0..1023
    const int lane = t & 63, w = t >> 6;

    f4 v = reinterpret_cast<const f4*>(equ)[t * 64 + cq];
    f4 s = v;
    f4 qs = v * v;

#pragma unroll
    for (int off = 32; off >= 1; off >>= 1) {
#pragma unroll
        for (int k = 0; k < 4; ++k) {
            s[k]  += __shfl_xor(s[k], off);
            qs[k] += __shfl_xor(qs[k], off);
        }
    }

    __shared__ f4 ws_[16][2];
    if (lane == 0) { ws_[w][0] = s; ws_[w][1] = qs; }
    __syncthreads();

    __shared__ f4 sc_s, sh_s;
    if (t == 0) {
        f4 S = (f4){0.f, 0.f, 0.f, 0.f};
        f4 Q = (f4){0.f, 0.f, 0.f, 0.f};
#pragma unroll
        for (int g = 0; g < 16; ++g) { S += ws_[g][0]; Q += ws_[g][1]; }
        const float inv_n = 1.f / (float)(BB * NN);
        f4 gm = reinterpret_cast<const f4*>(gamma)[cq];
        f4 bt = reinterpret_cast<const f4*>(beta)[cq];
        f4 sc, sh;
#pragma unroll
        for (int k = 0; k < 4; ++k) {
            float mean = S[k] * inv_n;
            float var  = Q[k] * inv_n - mean * mean;
            float rstd = rsqrtf(var + BN_EPS);
            sc[k] = rstd * gm[k];
            sh[k] = bt[k] - mean * rstd * gm[k];
        }
        sc_s = sc; sh_s = sh;
    }
    __syncthreads();

    f4 sc = sc_s, sh = sh_s;
    f4 o;
#pragma unroll
    for (int k = 0; k < 4; ++k) o[k] = v[k] * sc[k] + sh[k];
    reinterpret_cast<f4*>(out)[t * 64 + cq] = o;
}

// ---------------------------------------------------------------------------
extern "C" void kernel_launch(void* const* d_in, const int* in_sizes, int n_in,
                              void* d_out, int out_size, void* d_ws, size_t ws_size,
                              hipStream_t stream) {
    (void)in_sizes; (void)n_in; (void)out_size; (void)ws_size;

    const float* nodes = (const float*)d_in[0];
    const float* edges = (const float*)d_in[1];
    const float* W1    = (const float*)d_in[2];
    const float* W2    = (const float*)d_in[3];
    const float* gamma = (const float*)d_in[4];
    const float* beta  = (const float*)d_in[5];
    float* out = (float*)d_out;

    const int nBN_H = BB * NN * HH;  // 262144
    float* ws    = (float*)d_ws;
    float* xleft = ws;
    float* xw2   = ws + nBN_H;
    float* equ   = ws + 2 * nBN_H;
    float* WT1   = ws + 3 * nBN_H;
    float* WT2   = WT1 + HH * HH;

    transpose_kernel<<<32, 256, 0, stream>>>(W1, W2, WT1, WT2);
    proj_kernel<<<256, 256, 0, stream>>>(nodes, WT1, WT2, xleft, xw2);
    edge_kernel<<<BB * NN, 512, 0, stream>>>(edges, xw2, xleft, equ);
    statsnorm_kernel<<<64, 1024, 0, stream>>>(equ, gamma, beta, out);
}

// Round 7
// 73.413 us; speedup vs baseline: 1.0874x; 1.0874x over previous
//
#include <hip/hip_runtime.h>
#include <cstddef>

#define BB 4
#define NN 256
#define HH 256
#define BN_EPS 1e-5f
#define ETA_EPS 1e-20f

typedef float f4 __attribute__((ext_vector_type(4)));

__device__ __forceinline__ float fast_sigmoid(float x) {
    float ex = __expf(-x);
    return __builtin_amdgcn_rcpf(1.f + ex);
}

// ---------------------------------------------------------------------------
// Kernel 0: transpose W1,W2 -> WT1,WT2 (WT[h][o] = W[o][h]). 32 blocks.
// ---------------------------------------------------------------------------
__global__ __launch_bounds__(256) void transpose_kernel(
    const float* __restrict__ W1, const float* __restrict__ W2,
    float* __restrict__ WT1, float* __restrict__ WT2)
{
    const int which = blockIdx.x >> 4;
    const int tile  = blockIdx.x & 15;
    const int tr = (tile >> 2) << 6, tc = (tile & 3) << 6;
    const float* __restrict__ W  = which ? W2 : W1;
    float* __restrict__ WT       = which ? WT2 : WT1;

    __shared__ float tl[64][65];
    const int c = threadIdx.x & 63, p0 = threadIdx.x >> 6;
#pragma unroll
    for (int p = 0; p < 16; ++p) {
        int r = p * 4 + p0;
        tl[c][r] = W[(tr + r) * HH + tc + c];
    }
    __syncthreads();
#pragma unroll
    for (int p = 0; p < 16; ++p) {
        int cc = p * 4 + p0;
        WT[(tc + cc) * HH + tr + c] = tl[cc][c];
    }
}

// ---------------------------------------------------------------------------
// Kernel 1: projections via WT.  out[r][o] = sum_h x[r][h] * WT[h][o].
// grid = 256 blocks: [0,128) -> WT1/xleft, [128,256) -> WT2/xw2. (R5 proven)
// ---------------------------------------------------------------------------
__global__ __launch_bounds__(256) void proj_kernel(
    const float* __restrict__ nodes, const float* __restrict__ WT1,
    const float* __restrict__ WT2, float* __restrict__ xleft,
    float* __restrict__ xw2)
{
    const int which = blockIdx.x >> 7;
    const int rb    = blockIdx.x & 127;   // 8-row group
    const float* __restrict__ WT = which ? WT2 : WT1;
    float* __restrict__ out      = which ? xw2 : xleft;
    const int t = threadIdx.x;

    __shared__ float xs[8][HH];           // 8 KB
    {
        f4* xs4 = reinterpret_cast<f4*>(xs);
        const f4* nodes4 = reinterpret_cast<const f4*>(nodes) + rb * 512;
#pragma unroll
        for (int m = 0; m < 2; ++m) xs4[m * 256 + t] = nodes4[m * 256 + t];
    }
    __syncthreads();

    const int oq = t & 63;
    const int hg = t >> 6;
    const f4* __restrict__ WT4 = reinterpret_cast<const f4*>(WT);

    f4 acc[8];
#pragma unroll
    for (int r = 0; r < 8; ++r) acc[r] = (f4){0.f, 0.f, 0.f, 0.f};

    for (int hh = 0; hh < 64; ++hh) {
        const int h = hg * 64 + hh;
        f4 wv = WT4[h * 64 + oq];         // coalesced 1 KB per wave
#pragma unroll
        for (int r = 0; r < 8; ++r)
            acc[r] += xs[r][h] * wv;      // LDS broadcast
    }

    __shared__ f4 ps[4][8][64];           // 32 KB
#pragma unroll
    for (int r = 0; r < 8; ++r) ps[hg][r][oq] = acc[r];
    __syncthreads();

#pragma unroll
    for (int m = 0; m < 2; ++m) {
        int idx = m * 256 + t;
        int r = idx >> 6, o = idx & 63;
        f4 v = ps[0][r][o] + ps[1][r][o] + ps[2][r][o] + ps[3][r][o];
        reinterpret_cast<f4*>(out)[(rb * 8 + r) * 64 + o] = v;
    }
}

// ---------------------------------------------------------------------------
// Kernel 2: edge aggregation. 1024 blocks x 1024 thr (one block per i-row,
// 2 blocks/CU = 32 waves/CU). Wave = one FULL 1 KB channel row (lane q=t&63,
// 16 B each, fully coalesced); 16 j-groups strided (jg = t>>6), 16 iters,
// unroll 4 -> 4 KB in flight per wave. edges nontemporal (keeps 1 MB xw2
// L2-resident); xw2 plain loads hit L2. No xw LDS staging (R4: no benefit),
// no launch_bounds VGPR cap (R6: cost 25% occupancy). 32 KB f4 reduction.
// ---------------------------------------------------------------------------
__global__ __launch_bounds__(1024) void edge_kernel(
    const float* __restrict__ edges, const float* __restrict__ xw2,
    const float* __restrict__ xleft, float* __restrict__ equ)
{
    const int bi = blockIdx.x;         // b*N + i
    const int b  = bi >> 8;
    const int t  = threadIdx.x;
    const int q  = t & 63;             // f4 quad over all 256 channels
    const int jg = t >> 6;             // 0..15

    const f4* __restrict__ e4 =
        reinterpret_cast<const f4*>(edges) + ((size_t)bi * NN + jg) * 64 + q;
    const f4* __restrict__ xw4 =
        reinterpret_cast<const f4*>(xw2) + ((size_t)b * NN + jg) * 64 + q;

    f4 s0 = (f4){0.f, 0.f, 0.f, 0.f};
    f4 s1 = (f4){0.f, 0.f, 0.f, 0.f};

#pragma unroll 4
    for (int jj = 0; jj < 16; ++jj) {          // j = jg + jj*16
        f4 e  = __builtin_nontemporal_load(e4 + (size_t)jj * 16 * 64);
        f4 xw = xw4[(size_t)jj * 16 * 64];
#pragma unroll
        for (int k = 0; k < 4; ++k) {
            float sg = fast_sigmoid(e[k]);
            s0[k] += sg;
            s1[k] += sg * xw[k];
        }
    }

    __shared__ f4 red0[16][64];        // 16 KB
    __shared__ f4 red1[16][64];        // 16 KB
    red0[jg][q] = s0;
    red1[jg][q] = s1;
    __syncthreads();

    if (t < 64) {
        f4 S0 = (f4){0.f, 0.f, 0.f, 0.f};
        f4 S1 = (f4){0.f, 0.f, 0.f, 0.f};
#pragma unroll
        for (int g = 0; g < 16; ++g) { S0 += red0[g][t]; S1 += red1[g][t]; }
        f4 xl = reinterpret_cast<const f4*>(xleft)[bi * 64 + t];
        f4 o;
#pragma unroll
        for (int k = 0; k < 4; ++k) o[k] = xl[k] + S1[k] / (S0[k] + ETA_EPS);
        reinterpret_cast<f4*>(equ)[bi * 64 + t] = o;
    }
}

// ---------------------------------------------------------------------------
// Kernel 3: fused BN stats + normalize. 64 blocks x 1024 thr; block owns one
// f4 channel quad. Row quad held in register across both phases.
// ---------------------------------------------------------------------------
__global__ __launch_bounds__(1024) void statsnorm_kernel(
    const float* __restrict__ equ, const float* __restrict__ gamma,
    const float* __restrict__ beta, float* __restrict__ out)
{
    const int cq = blockIdx.x;          // channel quad 0..63
    const int t  = threadIdx.x;         // row 0..1023
    const int lane = t & 63, w = t >> 6;

    f4 v = reinterpret_cast<const f4*>(equ)[t * 64 + cq];
    f4 s = v;
    f4 qs = v * v;

#pragma unroll
    for (int off = 32; off >= 1; off >>= 1) {
#pragma unroll
        for (int k = 0; k < 4; ++k) {
            s[k]  += __shfl_xor(s[k], off);
            qs[k] += __shfl_xor(qs[k], off);
        }
    }

    __shared__ f4 ws_[16][2];
    if (lane == 0) { ws_[w][0] = s; ws_[w][1] = qs; }
    __syncthreads();

    __shared__ f4 sc_s, sh_s;
    if (t == 0) {
        f4 S = (f4){0.f, 0.f, 0.f, 0.f};
        f4 Q = (f4){0.f, 0.f, 0.f, 0.f};
#pragma unroll
        for (int g = 0; g < 16; ++g) { S += ws_[g][0]; Q += ws_[g][1]; }
        const float inv_n = 1.f / (float)(BB * NN);
        f4 gm = reinterpret_cast<const f4*>(gamma)[cq];
        f4 bt = reinterpret_cast<const f4*>(beta)[cq];
        f4 sc, sh;
#pragma unroll
        for (int k = 0; k < 4; ++k) {
            float mean = S[k] * inv_n;
            float var  = Q[k] * inv_n - mean * mean;
            float rstd = rsqrtf(var + BN_EPS);
            sc[k] = rstd * gm[k];
            sh[k] = bt[k] - mean * rstd * gm[k];
        }
        sc_s = sc; sh_s = sh;
    }
    __syncthreads();

    f4 sc = sc_s, sh = sh_s;
    f4 o;
#pragma unroll
    for (int k = 0; k < 4; ++k) o[k] = v[k] * sc[k] + sh[k];
    reinterpret_cast<f4*>(out)[t * 64 + cq] = o;
}

// ---------------------------------------------------------------------------
extern "C" void kernel_launch(void* const* d_in, const int* in_sizes, int n_in,
                              void* d_out, int out_size, void* d_ws, size_t ws_size,
                              hipStream_t stream) {
    (void)in_sizes; (void)n_in; (void)out_size; (void)ws_size;

    const float* nodes = (const float*)d_in[0];
    const float* edges = (const float*)d_in[1];
    const float* W1    = (const float*)d_in[2];
    const float* W2    = (const float*)d_in[3];
    const float* gamma = (const float*)d_in[4];
    const float* beta  = (const float*)d_in[5];
    float* out = (float*)d_out;

    const int nBN_H = BB * NN * HH;  // 262144
    float* ws    = (float*)d_ws;
    float* xleft = ws;
    float* xw2   = ws + nBN_H;
    float* equ   = ws + 2 * nBN_H;
    float* WT1   = ws + 3 * nBN_H;
    float* WT2   = WT1 + HH * HH;

    transpose_kernel<<<32, 256, 0, stream>>>(W1, W2, WT1, WT2);
    proj_kernel<<<256, 256, 0, stream>>>(nodes, WT1, WT2, xleft, xw2);
    edge_kernel<<<BB * NN, 1024, 0, stream>>>(edges, xw2, xleft, equ);
    statsnorm_kernel<<<64, 1024, 0, stream>>>(equ, gamma, beta, out);
}